// Round 17
// baseline (105.063 us; speedup 1.0000x reference)
//
#include <hip/hip_runtime.h>

// UpsampleRFFT (zero-insert 2x + ideal half-band low-pass, circular), closed form:
//   g[j] = sign*cot(pi*(2j+1)/256)/128, sign=+ if j even
//   out[2r][2i]   = x[r][i] (exact fp32)      out[2r][2i+1] = T[r][i],  T = X*G
//   out[2p+1][c]  = sum_m g[(p-m)&127] * E[m][c],  E = even rows
//
// R17 structure: TWO barrier-free streaming kernels (R13's phases split),
// E exchanged via global (128MB, L3-resident) instead of LDS:
//   K1: even rows, full-width (x read ONCE), no LDS/barrier, max TLP.
//   K2: odd rows; stages even rows (L3-hot, full-line 512B chunks) into the
//       R13-swizzled Et tile, one cheap barrier, identical phase-B MFMA.
// Lessons kept: rule #20 (static reg indices; runtime offsets in ADDRESSES),
// no nt stores (R10), Et XOR swizzle + 2-p-tile reuse (R13).

typedef __bf16 bf16x8 __attribute__((ext_vector_type(8)));
typedef float  f32x4  __attribute__((ext_vector_type(4)));

#define PI_F 3.14159265358979323846f

__device__ __forceinline__ unsigned short f2bf(float x) {
    unsigned int b = __float_as_uint(x);
    return (unsigned short)((b + 0x7FFFu + ((b >> 16) & 1u)) >> 16);  // RNE
}

__device__ __forceinline__ float gfun(int j) {           // g[j & 127]
    int d = 2 * (j & 127) + 1;
    float th = PI_F * (float)d * (1.0f / 256.0f);
    float s  = ((d & 3) == 1) ? 1.0f : -1.0f;
    return s * cosf(th) / (128.0f * sinf(th));
}

// byte-offset XOR swizzle within a 256B Et row (bits 4..6); same fn on W+R.
__device__ __forceinline__ int etswz(int row) {
    return (((row & 7) ^ (((row >> 3) & 3) << 1) ^ (((row >> 5) & 1) << 2)) << 4);
}

// ---- init: per-lane tap fragment table (8 frags x 64 lanes x 8 bf16 = 8KB) ----
__global__ __launch_bounds__(512)
void init_ghtab(unsigned short* __restrict__ ghtab)
{
    const int t    = threadIdx.x;         // t = dd*64 + lane
    const int lane = t & 63;
    const int l15  = lane & 15;
    const int l4   = lane >> 4;
    const int dd   = t >> 6;
    const int base = l15 - 8 * l4 + 16 * dd;
    unsigned short u[8];
    #pragma unroll
    for (int e = 0; e < 8; ++e) u[e] = f2bf(gfun(base - e));
    *(ushort4*)&ghtab[t * 8]     = make_ushort4(u[0], u[1], u[2], u[3]);
    *(ushort4*)&ghtab[t * 8 + 4] = make_ushort4(u[4], u[5], u[6], u[7]);
}

// ---- K1: even output rows. 2 blocks/image (row halves), 256 thr, NO LDS ----
__global__ __launch_bounds__(256)
void k1_even(const float* __restrict__ xin, float* __restrict__ out,
             const unsigned short* __restrict__ ghtab)
{
    const int tid  = threadIdx.x;
    const int lane = tid & 63;
    const int w    = tid >> 6;        // 0..3
    const int l15  = lane & 15;
    const int l4   = lane >> 4;

    const long long img = blockIdx.x >> 1;
    const int rh        = blockIdx.x & 1;
    const float* __restrict__ xim = xin + img * (128LL * 128LL);
    float*       __restrict__ oim = out + img * (256LL * 256LL);

    const int r = 64 * rh + 16 * w + l15;
    const float* __restrict__ xrow = xim + r * 128;

    // full-row x loads, all 8 dwordx4 in flight
    float4 xlo[4], xhi[4];
    #pragma unroll
    for (int t = 0; t < 4; ++t) {
        xlo[t] = *(const float4*)&xrow[32 * t + 8 * l4];
        xhi[t] = *(const float4*)&xrow[32 * t + 8 * l4 + 4];
    }

    // all 8 tap frags (static indices, full width — no cb fold needed)
    bf16x8 ghc[8];
    #pragma unroll
    for (int v = 0; v < 8; ++v)
        ghc[v] = *(const bf16x8*)&ghtab[(v * 64 + lane) * 8];

    // X fragments (transient union, register-resident)
    bf16x8 xa[4];
    #pragma unroll
    for (int t = 0; t < 4; ++t) {
        union { bf16x8 v; unsigned short u[8]; } H;
        H.u[0] = f2bf(xlo[t].x); H.u[1] = f2bf(xlo[t].y);
        H.u[2] = f2bf(xlo[t].z); H.u[3] = f2bf(xlo[t].w);
        H.u[4] = f2bf(xhi[t].x); H.u[5] = f2bf(xhi[t].y);
        H.u[6] = f2bf(xhi[t].z); H.u[7] = f2bf(xhi[t].w);
        xa[t] = H.v;
    }

    // T = X*G (transposed GEMM); write interleaved even rows, full 1KB width
    float* __restrict__ orow = oim + (2 * r) * 256;
    #pragma unroll
    for (int mt = 0; mt < 8; ++mt) {
        f32x4 acc = {0.f, 0.f, 0.f, 0.f};
        #pragma unroll
        for (int t = 0; t < 4; ++t)
            acc = __builtin_amdgcn_mfma_f32_16x16x32_bf16(ghc[(mt - 2 * t) & 7],
                                                          xa[t], acc, 0, 0, 0);
        const int i0 = 16 * mt + 4 * l4;
        float4 xc = *(const float4*)&xrow[i0];     // L1 hit, exact fp32 copies
        float4 o0 = make_float4(xc.x, acc[0], xc.y, acc[1]);
        float4 o1 = make_float4(xc.z, acc[2], xc.w, acc[3]);
        *(float4*)&orow[2 * i0]     = o0;
        *(float4*)&orow[2 * i0 + 4] = o1;
    }
}

// ---- K2: odd rows from even rows (L3-hot). 2 blocks/image (c-halves) ----
__global__ __launch_bounds__(512)
void k2_odd(float* __restrict__ out, const unsigned short* __restrict__ ghtab)
{
    __shared__ __align__(16) unsigned short Et[128 * 128]; // Et[c_loc][m], swizzled

    const int tid  = threadIdx.x;
    const int lane = tid & 63;
    const int w    = tid >> 6;
    const int l15  = lane & 15;
    const int l4   = lane >> 4;

    const long long img = blockIdx.x >> 1;
    const int cb        = blockIdx.x & 1;
    float* __restrict__ oim = out + img * (256LL * 256LL);

    // stage even rows for this c-half: full-line 512B chunks per row, L3-hot
    #pragma unroll
    for (int k = 0; k < 8; ++k) {
        const int fidx = k * 512 + tid;            // 4096 float4 = 128 rows x 32
        const int m    = fidx >> 5;
        const int c4   = fidx & 31;
        float4 v = *(const float4*)&oim[(2 * m) * 256 + 128 * cb + 4 * c4];
        float vv[4] = {v.x, v.y, v.z, v.w};
        #pragma unroll
        for (int e = 0; e < 4; ++e) {
            const int row = 4 * c4 + e;            // c_loc
            Et[row * 128 + (((2 * m) ^ etswz(row)) >> 1)] = f2bf(vv[e]);
        }
    }
    __syncthreads();   // only staging loads outstanding; cheap drain

    // phase B (identical to R13): odd[p][c] = sum_m g[(p-m)&127] * E[m][c]
    {
        const int pa = w & 3;
        const int mh = w >> 2;
        bf16x8 gbd[4];
        #pragma unroll
        for (int d = 0; d < 4; ++d) {
            const int dd = (pa + 2 * d) & 7;
            gbd[d] = *(const bf16x8*)&ghtab[(dd * 64 + lane) * 8];
        }
        float* __restrict__ prowA = oim + (2 * (16 * pa + l15) + 1) * 256 + 128 * cb;
        float* __restrict__ prowB = oim + (2 * (16 * (pa + 4) + l15) + 1) * 256 + 128 * cb;
        #pragma unroll
        for (int mci = 0; mci < 4; ++mci) {
            const int mc = 4 * mh + mci;
            const int row = 16 * mc + l15;
            const char* erow = (const char*)Et + row * 256;
            const int sw = etswz(row);
            f32x4 aA = {0.f, 0.f, 0.f, 0.f};
            f32x4 aB = {0.f, 0.f, 0.f, 0.f};
            #pragma unroll
            for (int t = 0; t < 4; ++t) {
                bf16x8 ef = *(const bf16x8*)(erow + ((64 * t + 16 * l4) ^ sw));
                aA = __builtin_amdgcn_mfma_f32_16x16x32_bf16(ef, gbd[(-t) & 3], aA, 0, 0, 0);
                aB = __builtin_amdgcn_mfma_f32_16x16x32_bf16(ef, gbd[(2 - t) & 3], aB, 0, 0, 0);
            }
            float4 oA = make_float4(aA[0], aA[1], aA[2], aA[3]);
            float4 oB = make_float4(aB[0], aB[1], aB[2], aB[3]);
            *(float4*)&prowA[16 * mc + 4 * l4] = oA;
            *(float4*)&prowB[16 * mc + 4 * l4] = oB;
        }
    }
}

extern "C" void kernel_launch(void* const* d_in, const int* in_sizes, int n_in,
                              void* d_out, int out_size, void* d_ws, size_t ws_size,
                              hipStream_t stream)
{
    (void)n_in; (void)out_size; (void)ws_size;
    const float* x = (const float*)d_in[0];
    float* out = (float*)d_out;
    int nimg = in_sizes[0] / (128 * 128);   // 1024 images

    unsigned short* ghtab = (unsigned short*)d_ws;   // 8KB; ws is ample
    hipLaunchKernelGGL(init_ghtab, dim3(1), dim3(512), 0, stream, ghtab);
    hipLaunchKernelGGL(k1_even, dim3(nimg * 2), dim3(256), 0, stream, x, out, ghtab);
    hipLaunchKernelGGL(k2_odd,  dim3(nimg * 2), dim3(512), 0, stream, out, ghtab);
}

// Round 18
// 91.238 us; speedup vs baseline: 1.1515x; 1.1515x over previous
//
#include <hip/hip_runtime.h>

// UpsampleRFFT (zero-insert 2x + ideal half-band low-pass, circular), closed form:
//   g[j] = sign*cot(pi*(2j+1)/256)/128, sign=+ if j even
//   out[2r][2i]   = x[r][i] (exact fp32)      out[2r][2i+1] = T[r][i],  T = X*G
//   out[2p+1][c]  = sum_m g[(p-m)&127] * E[m][c],  E = even rows
// 2 blocks per image (output-column halves), LDS = 32KB. R13 body (95.4us best).
//
// R5-R7 (rule #20): runtime-indexed register arrays -> scratch; all frag
// indices compile-time, runtime offsets folded into LOAD ADDRESSES.
// R10: nt stores hurt. R11: XCD swizzle neutral. R12: native casts neutral.
// R13: Et pitch 128 + XOR swizzle, phase-B 2-p-tile reuse. BEST.
// R14/R15: tap-pressure reduction hurt. R16: LDS-only barrier neutral.
// R17: two-kernel split hurt (E global round-trip > barrier cost).
// R18: tap table moved to COMPILE TIME (constexpr Taylor trig + arithmetic
// bf16-RNE) -> init kernel + its serial dependency (~5-10us/graph) removed.

typedef __bf16 bf16x8 __attribute__((ext_vector_type(8)));
typedef float  f32x4  __attribute__((ext_vector_type(4)));

#define PI_D 3.14159265358979323846

// ---- constexpr trig (Taylor, |x| <= pi, double: ~1e-11 rel) ----
constexpr double csin(double x) {
    double t = x, s = x; const double x2 = x * x;
    for (int k = 1; k < 13; ++k) { t *= -x2 / double((2 * k) * (2 * k + 1)); s += t; }
    return s;
}
constexpr double ccos(double x) {
    double t = 1.0, s = 1.0; const double x2 = x * x;
    for (int k = 1; k < 13; ++k) { t *= -x2 / double((2 * k - 1) * (2 * k)); s += t; }
    return s;
}
// ---- constexpr double -> bf16 (RNE), arithmetic (no bit_cast) ----
constexpr unsigned short d2bf(double v) {
    unsigned short sgn = 0;
    if (v < 0) { sgn = 0x8000; v = -v; }
    if (v == 0) return sgn;
    int e = 0;
    while (v >= 2.0) { v *= 0.5; ++e; }
    while (v < 1.0)  { v *= 2.0; --e; }
    double m = (v - 1.0) * 128.0;            // 7-bit mantissa
    int mi = (int)m;
    const double frac = m - (double)mi;
    if (frac > 0.5 || (frac == 0.5 && (mi & 1))) ++mi;
    if (mi == 128) { mi = 0; ++e; }
    return (unsigned short)(sgn | ((unsigned)(e + 127) << 7) | (unsigned)mi);
}
constexpr double gval(int j) {               // g[j & 127]
    const int d = 2 * (j & 127) + 1;
    const double th = PI_D * (double)d / 256.0;
    const double s = ((d & 3) == 1) ? 1.0 : -1.0;
    return s * ccos(th) / (128.0 * csin(th));
}
// per-lane tap fragment table: [dd*64 + lane]*8 + e = g[(l15-8*l4+16*dd - e)&127]
struct GhTab { unsigned short v[8 * 64 * 8]; };
constexpr GhTab make_ghtab() {
    GhTab t{};
    for (int dd = 0; dd < 8; ++dd)
        for (int lane = 0; lane < 64; ++lane) {
            const int l15 = lane & 15, l4 = lane >> 4;
            const int base = l15 - 8 * l4 + 16 * dd;
            for (int e = 0; e < 8; ++e)
                t.v[(dd * 64 + lane) * 8 + e] = d2bf(gval(base - e));
        }
    return t;
}
__device__ constexpr GhTab GHTAB = make_ghtab();

__device__ __forceinline__ unsigned short f2bf(float x) {
    unsigned int b = __float_as_uint(x);
    return (unsigned short)((b + 0x7FFFu + ((b >> 16) & 1u)) >> 16);  // RNE
}

// byte-offset XOR swizzle within a 256B Et row (bits 4..6); same fn on W+R.
__device__ __forceinline__ int etswz(int row) {
    return (((row & 7) ^ (((row >> 3) & 3) << 1) ^ (((row >> 5) & 1) << 2)) << 4);
}

// ---- fused kernel: 2 blocks/image (c-halves), 512 threads (8 waves) ----
__global__ __launch_bounds__(512, 4)
void upsample_fused(const float* __restrict__ xin, float* __restrict__ out)
{
    __shared__ __align__(16) unsigned short Et[128 * 128]; // Et[c_loc][m], swizzled

    const unsigned short* __restrict__ ghtab = GHTAB.v;

    const int tid  = threadIdx.x;
    const int lane = tid & 63;
    const int w    = tid >> 6;        // 0..7: r-tile (A); (pa,mh) in phase B
    const int l15  = lane & 15;
    const int l4   = lane >> 4;

    const long long img = blockIdx.x >> 1;
    const int cb        = blockIdx.x & 1;          // column half
    const float* __restrict__ xim = xin + img * (128LL * 128LL);
    float*       __restrict__ oim = out + img * (256LL * 256LL);

    const int r = 16 * w + l15;
    const float* __restrict__ xrow = xim + r * 128;

    // issue full-row x loads first (K=128 needed for the W-conv)
    float4 xlo[4], xhi[4];
    #pragma unroll
    for (int t = 0; t < 4; ++t) {
        xlo[t] = *(const float4*)&xrow[32 * t + 8 * l4];
        xhi[t] = *(const float4*)&xrow[32 * t + 8 * l4 + 4];
    }

    // Phase-A tap frags: cb folded into the ADDRESS; register indices static.
    bf16x8 ghc[8];
    #pragma unroll
    for (int v = 0; v < 8; ++v) {
        const int dd = (v + 4 * cb) & 7;
        ghc[v] = *(const bf16x8*)&ghtab[(dd * 64 + lane) * 8];
    }

    // X fragments (transient union, register-resident) + even cols of E^T.
    bf16x8 xa[4];
    #pragma unroll
    for (int t = 0; t < 4; ++t) {
        union { bf16x8 v; unsigned short u[8]; } H;
        H.u[0] = f2bf(xlo[t].x); H.u[1] = f2bf(xlo[t].y);
        H.u[2] = f2bf(xlo[t].z); H.u[3] = f2bf(xlo[t].w);
        H.u[4] = f2bf(xhi[t].x); H.u[5] = f2bf(xhi[t].y);
        H.u[6] = f2bf(xhi[t].z); H.u[7] = f2bf(xhi[t].w);
        xa[t] = H.v;
        if ((t >> 1) == cb) {                      // this t covers our c-half
            const int tt = t & 1;
            #pragma unroll
            for (int e = 0; e < 8; ++e) {
                const int row = 64 * tt + 16 * l4 + 2 * e;
                Et[row * 128 + (((2 * r) ^ etswz(row)) >> 1)] = H.u[e];
            }
        }
    }

    // ---- phase A: T = X*G (transposed); even output rows + odd cols of E^T ----
    float* __restrict__ orow = oim + (2 * r) * 256 + 128 * cb;
    #pragma unroll
    for (int mt = 0; mt < 4; ++mt) {
        f32x4 acc = {0.f, 0.f, 0.f, 0.f};
        #pragma unroll
        for (int t = 0; t < 4; ++t)
            acc = __builtin_amdgcn_mfma_f32_16x16x32_bf16(ghc[(mt - 2 * t) & 7],
                                                          xa[t], acc, 0, 0, 0);
        const int i0l = 16 * mt + 4 * l4;          // local i in [0,64)
        float4 xc = *(const float4*)&xrow[64 * cb + i0l];   // L1 hit, exact fp32
        float4 o0 = make_float4(xc.x, acc[0], xc.y, acc[1]);
        float4 o1 = make_float4(xc.z, acc[2], xc.w, acc[3]);
        *(float4*)&orow[2 * i0l]     = o0;
        *(float4*)&orow[2 * i0l + 4] = o1;
        #pragma unroll
        for (int q = 0; q < 4; ++q) {
            const int row = 2 * (i0l + q) + 1;
            Et[row * 128 + (((2 * r) ^ etswz(row)) >> 1)] = f2bf(acc[q]);
        }
    }
    __syncthreads();

    // ---- phase B: odd[p][c] = sum_m g[(p-m)&127] * E[m][c]
    //      2-p-tile reuse: wave -> p-tiles {pa, pa+4}, mc range 4*mh..4*mh+3 ----
    {
        const int pa = w & 3;
        const int mh = w >> 2;
        // 4 tap frags cover both p-tiles: gbd[d] = frag[(pa+2d)&7].
        bf16x8 gbd[4];
        #pragma unroll
        for (int d = 0; d < 4; ++d) {
            const int dd = (pa + 2 * d) & 7;
            gbd[d] = *(const bf16x8*)&ghtab[(dd * 64 + lane) * 8];
        }
        float* __restrict__ prowA = oim + (2 * (16 * pa + l15) + 1) * 256 + 128 * cb;
        float* __restrict__ prowB = oim + (2 * (16 * (pa + 4) + l15) + 1) * 256 + 128 * cb;
        #pragma unroll
        for (int mci = 0; mci < 4; ++mci) {
            const int mc = 4 * mh + mci;
            const int row = 16 * mc + l15;
            const char* erow = (const char*)Et + row * 256;
            const int sw = etswz(row);
            f32x4 aA = {0.f, 0.f, 0.f, 0.f};
            f32x4 aB = {0.f, 0.f, 0.f, 0.f};
            #pragma unroll
            for (int t = 0; t < 4; ++t) {
                bf16x8 ef = *(const bf16x8*)(erow + ((64 * t + 16 * l4) ^ sw));
                // pa: dd=(pa-2t)&7 -> d=(-t)&3 ; pa+4: dd=(pa+4-2t)&7 -> d=(2-t)&3
                aA = __builtin_amdgcn_mfma_f32_16x16x32_bf16(ef, gbd[(-t) & 3], aA, 0, 0, 0);
                aB = __builtin_amdgcn_mfma_f32_16x16x32_bf16(ef, gbd[(2 - t) & 3], aB, 0, 0, 0);
            }
            float4 oA = make_float4(aA[0], aA[1], aA[2], aA[3]);
            float4 oB = make_float4(aB[0], aB[1], aB[2], aB[3]);
            *(float4*)&prowA[16 * mc + 4 * l4] = oA;
            *(float4*)&prowB[16 * mc + 4 * l4] = oB;
        }
    }
}

extern "C" void kernel_launch(void* const* d_in, const int* in_sizes, int n_in,
                              void* d_out, int out_size, void* d_ws, size_t ws_size,
                              hipStream_t stream)
{
    (void)n_in; (void)out_size; (void)d_ws; (void)ws_size;
    const float* x = (const float*)d_in[0];
    float* out = (float*)d_out;
    int nimg = in_sizes[0] / (128 * 128);   // 1024 images

    hipLaunchKernelGGL(upsample_fused, dim3(nimg * 2), dim3(512), 0, stream, x, out);
}

// Round 19
// 91.048 us; speedup vs baseline: 1.1539x; 1.0021x over previous
//
#include <hip/hip_runtime.h>

// UpsampleRFFT (zero-insert 2x + ideal half-band low-pass, circular), closed form:
//   g[j] = sign*cot(pi*(2j+1)/256)/128, sign=+ if j even
//   out[2r][2i]   = x[r][i] (exact fp32)      out[2r][2i+1] = T[r][i],  T = X*G
//   out[2p+1][c]  = sum_m g[(p-m)&127] * E[m][c],  E = even rows
// R19: 4 blocks per image (output-column QUARTERS), LDS = 16KB. Finer phase
// granularity -> barrier stalls halve and interleave better across the
// 4 blocks/CU (R4->R8 precedent: 1->2 split gave +9%). Per-thread serial head
// unchanged; tap base 2qb folded into LOAD ADDRESSES (rule #20).
//
// Kept lessons: R10 no nt stores; R13 Et XOR swizzle + 2-p-tile frag reuse;
// R16 barrier variant neutral (plain __syncthreads); R18 constexpr tap table
// (no init kernel).

typedef __bf16 bf16x8 __attribute__((ext_vector_type(8)));
typedef float  f32x4  __attribute__((ext_vector_type(4)));

#define PI_D 3.14159265358979323846

// ---- constexpr trig (Taylor, |x| <= pi, double: ~1e-11 rel) ----
constexpr double csin(double x) {
    double t = x, s = x; const double x2 = x * x;
    for (int k = 1; k < 13; ++k) { t *= -x2 / double((2 * k) * (2 * k + 1)); s += t; }
    return s;
}
constexpr double ccos(double x) {
    double t = 1.0, s = 1.0; const double x2 = x * x;
    for (int k = 1; k < 13; ++k) { t *= -x2 / double((2 * k - 1) * (2 * k)); s += t; }
    return s;
}
// ---- constexpr double -> bf16 (RNE), arithmetic (no bit_cast) ----
constexpr unsigned short d2bf(double v) {
    unsigned short sgn = 0;
    if (v < 0) { sgn = 0x8000; v = -v; }
    if (v == 0) return sgn;
    int e = 0;
    while (v >= 2.0) { v *= 0.5; ++e; }
    while (v < 1.0)  { v *= 2.0; --e; }
    double m = (v - 1.0) * 128.0;            // 7-bit mantissa
    int mi = (int)m;
    const double frac = m - (double)mi;
    if (frac > 0.5 || (frac == 0.5 && (mi & 1))) ++mi;
    if (mi == 128) { mi = 0; ++e; }
    return (unsigned short)(sgn | ((unsigned)(e + 127) << 7) | (unsigned)mi);
}
constexpr double gval(int j) {               // g[j & 127]
    const int d = 2 * (j & 127) + 1;
    const double th = PI_D * (double)d / 256.0;
    const double s = ((d & 3) == 1) ? 1.0 : -1.0;
    return s * ccos(th) / (128.0 * csin(th));
}
// per-lane tap fragment table: [dd*64 + lane]*8 + e = g[(l15-8*l4+16*dd - e)&127]
struct GhTab { unsigned short v[8 * 64 * 8]; };
constexpr GhTab make_ghtab() {
    GhTab t{};
    for (int dd = 0; dd < 8; ++dd)
        for (int lane = 0; lane < 64; ++lane) {
            const int l15 = lane & 15, l4 = lane >> 4;
            const int base = l15 - 8 * l4 + 16 * dd;
            for (int e = 0; e < 8; ++e)
                t.v[(dd * 64 + lane) * 8 + e] = d2bf(gval(base - e));
        }
    return t;
}
__device__ constexpr GhTab GHTAB = make_ghtab();

__device__ __forceinline__ unsigned short f2bf(float x) {
    unsigned int b = __float_as_uint(x);
    return (unsigned short)((b + 0x7FFFu + ((b >> 16) & 1u)) >> 16);  // RNE
}

// byte-offset XOR swizzle within a 256B Et row (bits 4..6); same fn on W+R.
__device__ __forceinline__ int etswz(int row) {
    return (((row & 7) ^ (((row >> 3) & 3) << 1) ^ (((row >> 5) & 1) << 2)) << 4);
}

// ---- fused kernel: 4 blocks/image (c-quarters), 512 threads (8 waves) ----
__global__ __launch_bounds__(512, 4)
void upsample_fused(const float* __restrict__ xin, float* __restrict__ out)
{
    __shared__ __align__(16) unsigned short Et[64 * 128]; // Et[c_loc][m], 16KB

    const unsigned short* __restrict__ ghtab = GHTAB.v;

    const int tid  = threadIdx.x;
    const int lane = tid & 63;
    const int w    = tid >> 6;        // 0..7: r-tile (A); (pa,mh) in phase B
    const int l15  = lane & 15;
    const int l4   = lane >> 4;

    const long long img = blockIdx.x >> 2;
    const int qb        = blockIdx.x & 3;          // column quarter
    const float* __restrict__ xim = xin + img * (128LL * 128LL);
    float*       __restrict__ oim = out + img * (256LL * 256LL);

    const int r = 16 * w + l15;
    const float* __restrict__ xrow = xim + r * 128;

    // issue full-row x loads first (K=128 needed for the W-conv)
    float4 xlo[4], xhi[4];
    #pragma unroll
    for (int t = 0; t < 4; ++t) {
        xlo[t] = *(const float4*)&xrow[32 * t + 8 * l4];
        xhi[t] = *(const float4*)&xrow[32 * t + 8 * l4 + 4];
    }

    // Phase-A tap frags: 2qb folded into the ADDRESS; register indices static.
    bf16x8 ghc[8];
    #pragma unroll
    for (int v = 0; v < 8; ++v) {
        const int dd = (v + 2 * qb) & 7;
        ghc[v] = *(const bf16x8*)&ghtab[(dd * 64 + lane) * 8];
    }

    // X fragments (transient union, register-resident) + even cols of E^T
    // for this quarter (only t == qb covers c_loc even rows).
    bf16x8 xa[4];
    #pragma unroll
    for (int t = 0; t < 4; ++t) {
        union { bf16x8 v; unsigned short u[8]; } H;
        H.u[0] = f2bf(xlo[t].x); H.u[1] = f2bf(xlo[t].y);
        H.u[2] = f2bf(xlo[t].z); H.u[3] = f2bf(xlo[t].w);
        H.u[4] = f2bf(xhi[t].x); H.u[5] = f2bf(xhi[t].y);
        H.u[6] = f2bf(xhi[t].z); H.u[7] = f2bf(xhi[t].w);
        xa[t] = H.v;
        if (t == qb) {                             // i = 32qb+8l4+e -> c_loc even
            #pragma unroll
            for (int e = 0; e < 8; ++e) {
                const int row = 16 * l4 + 2 * e;   // c_loc = 2*(8*l4+e) - 64*qb... local
                Et[row * 128 + (((2 * r) ^ etswz(row)) >> 1)] = H.u[e];
            }
        }
    }

    // ---- phase A: T = X*G (transposed); quarter = odd-col tiles {2qb, 2qb+1} ----
    float* __restrict__ orow = oim + (2 * r) * 256;
    #pragma unroll
    for (int j = 0; j < 2; ++j) {
        f32x4 acc = {0.f, 0.f, 0.f, 0.f};
        #pragma unroll
        for (int t = 0; t < 4; ++t)   // dd = (2qb+j-2t)&7 -> ghc[(j-2t)&7]
            acc = __builtin_amdgcn_mfma_f32_16x16x32_bf16(ghc[(j - 2 * t) & 7],
                                                          xa[t], acc, 0, 0, 0);
        const int i0g = 32 * qb + 16 * j + 4 * l4; // global odd-col index i
        float4 xc = *(const float4*)&xrow[i0g];    // L1 hit, exact fp32 copies
        float4 o0 = make_float4(xc.x, acc[0], xc.y, acc[1]);
        float4 o1 = make_float4(xc.z, acc[2], xc.w, acc[3]);
        *(float4*)&orow[2 * i0g]     = o0;
        *(float4*)&orow[2 * i0g + 4] = o1;
        #pragma unroll
        for (int q = 0; q < 4; ++q) {              // c_loc = 2*(16j+4l4+q)+1
            const int row = 2 * (16 * j + 4 * l4 + q) + 1;
            Et[row * 128 + (((2 * r) ^ etswz(row)) >> 1)] = f2bf(acc[q]);
        }
    }
    __syncthreads();

    // ---- phase B: odd[p][c] = sum_m g[(p-m)&127] * E[m][c], quarter cols ----
    //      wave -> p-tiles {pa, pa+4} (frag reuse), mc tiles {2mh, 2mh+1}
    {
        const int pa = w & 3;
        const int mh = w >> 2;
        bf16x8 gbd[4];
        #pragma unroll
        for (int d = 0; d < 4; ++d) {
            const int dd = (pa + 2 * d) & 7;
            gbd[d] = *(const bf16x8*)&ghtab[(dd * 64 + lane) * 8];
        }
        float* __restrict__ prowA = oim + (2 * (16 * pa + l15) + 1) * 256 + 64 * qb;
        float* __restrict__ prowB = oim + (2 * (16 * (pa + 4) + l15) + 1) * 256 + 64 * qb;
        #pragma unroll
        for (int mci = 0; mci < 2; ++mci) {
            const int mc = 2 * mh + mci;           // local c-tile 0..3
            const int row = 16 * mc + l15;         // c_loc in [0,64)
            const char* erow = (const char*)Et + row * 256;
            const int sw = etswz(row);
            f32x4 aA = {0.f, 0.f, 0.f, 0.f};
            f32x4 aB = {0.f, 0.f, 0.f, 0.f};
            #pragma unroll
            for (int t = 0; t < 4; ++t) {
                bf16x8 ef = *(const bf16x8*)(erow + ((64 * t + 16 * l4) ^ sw));
                // pa: dd=(pa-2t)&7 -> d=(-t)&3 ; pa+4: dd=(pa+4-2t)&7 -> d=(2-t)&3
                aA = __builtin_amdgcn_mfma_f32_16x16x32_bf16(ef, gbd[(-t) & 3], aA, 0, 0, 0);
                aB = __builtin_amdgcn_mfma_f32_16x16x32_bf16(ef, gbd[(2 - t) & 3], aB, 0, 0, 0);
            }
            float4 oA = make_float4(aA[0], aA[1], aA[2], aA[3]);
            float4 oB = make_float4(aB[0], aB[1], aB[2], aB[3]);
            *(float4*)&prowA[16 * mc + 4 * l4] = oA;
            *(float4*)&prowB[16 * mc + 4 * l4] = oB;
        }
    }
}

extern "C" void kernel_launch(void* const* d_in, const int* in_sizes, int n_in,
                              void* d_out, int out_size, void* d_ws, size_t ws_size,
                              hipStream_t stream)
{
    (void)n_in; (void)out_size; (void)d_ws; (void)ws_size;
    const float* x = (const float*)d_in[0];
    float* out = (float*)d_out;
    int nimg = in_sizes[0] / (128 * 128);   // 1024 images

    hipLaunchKernelGGL(upsample_fused, dim3(nimg * 4), dim3(512), 0, stream, x, out);
}